// Round 9
// baseline (965.876 us; speedup 1.0000x reference)
//
#include <hip/hip_runtime.h>

#define N 50000
#define E 800000
#define H 128
#define G 64
#define OUTC 10
#define L 6
#define EPS 1e-5f

typedef unsigned short ushort_t;
typedef __attribute__((ext_vector_type(8))) short short8;
typedef __attribute__((ext_vector_type(4))) float floatx4;

__device__ __forceinline__ void atomAddF(float* p, float v) {
  unsafeAtomicAdd(p, v);   // hw global_atomic_add_f32 on gfx950
}

__device__ __forceinline__ unsigned short f2bf(float f) {
  unsigned u = __float_as_uint(f);
  unsigned r = (u + 0x7FFF + ((u >> 16) & 1)) >> 16;  // RNE
  return (unsigned short)r;
}
__device__ __forceinline__ float bf2f(unsigned short b) {
  return __uint_as_float(((unsigned)b) << 16);
}

// ---------------- init ----------------
__global__ void deg_count_kernel(const int* __restrict__ dst, int* __restrict__ deg) {
  int e = blockIdx.x * blockDim.x + threadIdx.x;
  if (e < E) atomicAdd(&deg[dst[e]], 1);
}

// prep: conv_W -> bf16x2 split, transposed: WThi/WTlo [l][n][k]
__global__ void prep_kernel(const float* __restrict__ convW,
                            ushort_t* __restrict__ WThi, ushort_t* __restrict__ WTlo) {
  int j = blockIdx.x * 256 + threadIdx.x;
  if (j < L * H * H) {
    int l = j >> 14, r = j & 16383;   // H*H = 16384
    int n = r >> 7, k = r & 127;
    float w = convW[l * 16384 + k * 128 + n];
    unsigned short hi = f2bf(w);
    WThi[j] = hi;
    WTlo[j] = f2bf(w - bf2f(hi));
  }
}

// ---------------- scan: deg[N] -> rowptr[N+1]  (2 kernels) ----------------
#define SCAN_B ((N + 255) / 256)   // 196

__global__ __launch_bounds__(256) void scanA_kernel(const int* __restrict__ deg,
                                                    int* __restrict__ blocksum,
                                                    float* __restrict__ dinv) {
  __shared__ int red[256];
  int i = blockIdx.x * 256 + threadIdx.x;
  int v = (i < N) ? deg[i] : 0;
  if (i < N) dinv[i] = rsqrtf((float)(v + 1));
  red[threadIdx.x] = v;
  __syncthreads();
  for (int off = 128; off > 0; off >>= 1) {
    if (threadIdx.x < off) red[threadIdx.x] += red[threadIdx.x + off];
    __syncthreads();
  }
  if (threadIdx.x == 0) blocksum[blockIdx.x] = red[0];
}

__global__ __launch_bounds__(256) void scanC_kernel(const int* __restrict__ deg,
                                                    const int* __restrict__ blocksum,
                                                    int* __restrict__ rowptr) {
  __shared__ int pre[256];
  __shared__ int sh[256];
  const int bid = blockIdx.x, t = threadIdx.x;
  pre[t] = (t < bid) ? blocksum[t] : 0;   // bid < SCAN_B <= 256
  __syncthreads();
  for (int off = 128; off > 0; off >>= 1) {
    if (t < off) pre[t] += pre[t + off];
    __syncthreads();
  }
  int base = pre[0];
  int i = bid * 256 + t;
  int d = (i < N) ? deg[i] : 0;
  sh[t] = d;
  __syncthreads();
  for (int off = 1; off < 256; off <<= 1) {
    int v = (t >= off) ? sh[t - off] : 0;
    __syncthreads();
    sh[t] += v;
    __syncthreads();
  }
  if (i < N) rowptr[i] = base + sh[t] - d;
  if (i == 0) rowptr[N] = E;
}

__global__ void csr_fill_kernel(const int* __restrict__ src, const int* __restrict__ dst,
                                const int* __restrict__ rowptr,
                                int* __restrict__ cursor, int* __restrict__ csr) {
  int e = blockIdx.x * blockDim.x + threadIdx.x;
  if (e < E) {
    int d = dst[e];
    int pos = rowptr[d] + atomicAdd(&cursor[d], 1);
    csr[pos] = src[e];
  }
}

__global__ void cnt_kernel(const int* __restrict__ batch, float* __restrict__ cnt) {
  __shared__ int lb[G + 1];
  int t = threadIdx.x;  // 128 threads
  if (t <= G) {
    int lo = 0, hi = N;
    while (lo < hi) { int m = (lo + hi) >> 1; if (batch[m] < t) lo = m + 1; else hi = m; }
    lb[t] = lo;
  }
  __syncthreads();
  if (t < G) cnt[t] = (float)(lb[t + 1] - lb[t]);
}

// ---------------- MFMA GEMM (bf16x3 split precision, fp32-equivalent) ----------------
// hWs[row] = dinv[row] * (f(A)@W)[row]   (fp32 out)
// A fp32; f = identity (bnsums==null) or BN+ReLU in fp32 on A fragments.
// A = Ahi + Alo, W = Whi + Wlo (bf16 RNE + residual); D = Ahi*Whi + Ahi*Wlo + Alo*Whi.
// block: 256 thr = 4 waves; block tile 64 rows; wave tile 16 rows x 128 cols.
// A frag: A[m=lane&15][k=quad*8+j]; C/D: col=lane&15, row=quad*4+reg.
__global__ __launch_bounds__(256) void gemm_mfma_kernel(
    const float* __restrict__ A,
    const ushort_t* __restrict__ WThi, const ushort_t* __restrict__ WTlo,
    const float* __restrict__ dinv, float* __restrict__ hWs,
    const float* __restrict__ bnsums, const float* __restrict__ gamma,
    const float* __restrict__ beta)
{
  const int tid = threadIdx.x;
  const int wave = tid >> 6, lane = tid & 63;
  const int quad = lane >> 4, m = lane & 15;
  const int row0 = blockIdx.x * 64 + wave * 16;
  const int arow = min(row0 + m, N - 1);
  const float invN = 1.0f / (float)N;

  short8 ahi[4], alo[4];
#pragma unroll
  for (int kc = 0; kc < 4; ++kc) {
    const int k0 = kc * 32 + quad * 8;
    float4 f0 = *(const float4*)&A[arow * H + k0];
    float4 f1 = *(const float4*)&A[arow * H + k0 + 4];
    float vals[8] = {f0.x, f0.y, f0.z, f0.w, f1.x, f1.y, f1.z, f1.w};
    if (bnsums) {
#pragma unroll
      for (int j = 0; j < 8; ++j) {
        float s = bnsums[k0 + j], q = bnsums[128 + k0 + j];
        float mu = s * invN;
        float var = q * invN - mu * mu;
        float rs = rsqrtf(var + EPS);
        float sc = gamma[k0 + j] * rs;
        float sh = beta[k0 + j] - mu * sc;
        vals[j] = fmaxf(vals[j] * sc + sh, 0.f);
      }
    }
    short8 h, l;
#pragma unroll
    for (int j = 0; j < 8; ++j) {
      unsigned short hb = f2bf(vals[j]);
      h[j] = (short)hb;
      l[j] = (short)f2bf(vals[j] - bf2f(hb));
    }
    ahi[kc] = h;
    alo[kc] = l;
  }

  float dv[4];
#pragma unroll
  for (int i = 0; i < 4; ++i) {
    int r = row0 + quad * 4 + i;
    dv[i] = (r < N) ? dinv[r] : 0.f;
  }

  const short* WH = (const short*)WThi;
  const short* WL = (const short*)WTlo;
#pragma unroll
  for (int nt = 0; nt < 8; ++nt) {
    floatx4 acc = {0.f, 0.f, 0.f, 0.f};
#pragma unroll
    for (int kc = 0; kc < 4; ++kc) {
      const int boff = (nt * 16 + m) * H + kc * 32 + quad * 8;
      short8 bhi = *(const short8*)&WH[boff];
      short8 blo = *(const short8*)&WL[boff];
      acc = __builtin_amdgcn_mfma_f32_16x16x32_bf16(ahi[kc], bhi, acc, 0, 0, 0);
      acc = __builtin_amdgcn_mfma_f32_16x16x32_bf16(alo[kc], bhi, acc, 0, 0, 0);
      acc = __builtin_amdgcn_mfma_f32_16x16x32_bf16(ahi[kc], blo, acc, 0, 0, 0);
    }
    int col = nt * 16 + m;
#pragma unroll
    for (int i = 0; i < 4; ++i) {
      int r = row0 + quad * 4 + i;
      if (r < N) hWs[r * H + col] = acc[i] * dv[i];
    }
  }
}

// ---------------- CSR gather (fp32) ----------------
// agg[n] = dinv[n]*(sum_e hWs[src_e] + hWs[n]) + bias
// 32 lanes per node, float4 per lane; grid exact (N*32/256 = 6250)
__global__ __launch_bounds__(256) void gather_kernel(
    const float* __restrict__ hWs, const int* __restrict__ csr,
    const int* __restrict__ rowptr, const float* __restrict__ dinv,
    const float* __restrict__ bias, float* __restrict__ agg)
{
  int t = blockIdx.x * 256 + threadIdx.x;
  int n = t >> 5, c4 = (t & 31) * 4;

  float4 self = *(const float4*)&hWs[n * H + c4];
  float ax = self.x, ay = self.y, az = self.z, aw = self.w;

  int e = rowptr[n], end = rowptr[n + 1];
  for (; e + 7 < end; e += 8) {
    int s0 = csr[e], s1 = csr[e + 1], s2 = csr[e + 2], s3 = csr[e + 3];
    int s4 = csr[e + 4], s5 = csr[e + 5], s6 = csr[e + 6], s7 = csr[e + 7];
    float4 u0 = *(const float4*)&hWs[s0 * H + c4];
    float4 u1 = *(const float4*)&hWs[s1 * H + c4];
    float4 u2 = *(const float4*)&hWs[s2 * H + c4];
    float4 u3 = *(const float4*)&hWs[s3 * H + c4];
    float4 u4 = *(const float4*)&hWs[s4 * H + c4];
    float4 u5 = *(const float4*)&hWs[s5 * H + c4];
    float4 u6 = *(const float4*)&hWs[s6 * H + c4];
    float4 u7 = *(const float4*)&hWs[s7 * H + c4];
    ax += ((u0.x + u1.x) + (u2.x + u3.x)) + ((u4.x + u5.x) + (u6.x + u7.x));
    ay += ((u0.y + u1.y) + (u2.y + u3.y)) + ((u4.y + u5.y) + (u6.y + u7.y));
    az += ((u0.z + u1.z) + (u2.z + u3.z)) + ((u4.z + u5.z) + (u6.z + u7.z));
    aw += ((u0.w + u1.w) + (u2.w + u3.w)) + ((u4.w + u5.w) + (u6.w + u7.w));
  }
  for (; e + 1 < end; e += 2) {
    int s0 = csr[e], s1 = csr[e + 1];
    float4 u0 = *(const float4*)&hWs[s0 * H + c4];
    float4 u1 = *(const float4*)&hWs[s1 * H + c4];
    ax += u0.x + u1.x; ay += u0.y + u1.y;
    az += u0.z + u1.z; aw += u0.w + u1.w;
  }
  if (e < end) {
    int s0 = csr[e];
    float4 u0 = *(const float4*)&hWs[s0 * H + c4];
    ax += u0.x; ay += u0.y; az += u0.z; aw += u0.w;
  }

  float dn = dinv[n];
  float4 bv = *(const float4*)&bias[c4];
  float4 o = make_float4(ax * dn + bv.x, ay * dn + bv.y,
                         az * dn + bv.z, aw * dn + bv.w);
  *(float4*)&agg[n * H + c4] = o;
}

// ---------------- batchnorm stats over fp32 agg ----------------
__global__ __launch_bounds__(256) void bn_stats_kernel(
    const float* __restrict__ a, float* __restrict__ sums)
{
  __shared__ float red[256];
  int tid = threadIdx.x;
  int c = tid & 127, half = tid >> 7;
  int r0 = blockIdx.x * 128;
  float s = 0.f, q = 0.f;
  for (int i = 0; i < 64; ++i) {
    int r = r0 + i * 2 + half;
    if (r < N) { float v = a[r * H + c]; s += v; q += v * v; }
  }
  red[tid] = s; __syncthreads();
  float s2 = (half == 0) ? s + red[tid + 128] : 0.f;
  __syncthreads();
  red[tid] = q; __syncthreads();
  if (half == 0) {
    float q2 = q + red[tid + 128];
    atomAddF(&sums[c], s2);
    atomAddF(&sums[128 + c], q2);
  }
}

// ---------------- global mean pool: chunked run-length accumulate (batch sorted) --------
__global__ __launch_bounds__(256) void pool_kernel(
    const float* __restrict__ h, const int* __restrict__ batch,
    float* __restrict__ pooled /* pre-zeroed */)
{
  int r0 = blockIdx.x * 128;
  int rend = min(r0 + 128, N);
  int c = threadIdx.x & 127, half = threadIdx.x >> 7;
  float acc = 0.f;
  int curg = -1;
  for (int r = r0 + half; r < rend; r += 2) {
    int g = batch[r];
    if (g != curg) {
      if (curg >= 0) atomAddF(&pooled[curg * H + c], acc);
      acc = 0.f; curg = g;
    }
    acc += h[r * H + c];
  }
  if (curg >= 0) atomAddF(&pooled[curg * H + c], acc);
}

// ---------------- head (4 small kernels, parallel across CUs) ----------------
__global__ void head1_kernel(const float* __restrict__ pooled, const float* __restrict__ cnt,
                             const float* __restrict__ W1, const float* __restrict__ b1,
                             float* __restrict__ z1)
{
  int t = blockIdx.x * 256 + threadIdx.x;  // 8192
  int g = t >> 7, c = t & 127;
  float s = 0.f;
  for (int k = 0; k < H; ++k) s += pooled[g * H + k] * W1[k * H + c];
  z1[t] = s / fmaxf(cnt[g], 1.0f) + b1[c];
}

__global__ void head_bn_kernel(float* __restrict__ z1,
                               const float* __restrict__ gamma, const float* __restrict__ beta)
{
  int c = threadIdx.x;  // 128 threads
  float s = 0.f, q = 0.f;
  for (int g = 0; g < G; ++g) { float v = z1[g * H + c]; s += v; q += v * v; }
  float mu = s / (float)G;
  float var = q / (float)G - mu * mu;
  float rs = rsqrtf(var + EPS);
  float ga = gamma[c], be = beta[c];
  for (int g = 0; g < G; ++g) {
    float v = z1[g * H + c];
    z1[g * H + c] = fmaxf((v - mu) * rs * ga + be, 0.f);
  }
}

__global__ void head2_kernel(const float* __restrict__ z1, const float* __restrict__ W2,
                             const float* __restrict__ b2, float* __restrict__ z2)
{
  int t = blockIdx.x * 256 + threadIdx.x;  // 8192
  int g = t >> 7, c = t & 127;
  float s = b2[c];
  for (int k = 0; k < H; ++k) s += z1[g * H + k] * W2[k * H + c];
  z2[t] = fmaxf(s, 0.f);
}

__global__ void head3_kernel(const float* __restrict__ z2, const float* __restrict__ W3,
                             const float* __restrict__ b3, float* __restrict__ out)
{
  int t = blockIdx.x * 256 + threadIdx.x;
  if (t < G * OUTC) {
    int g = t / OUTC, o = t % OUTC;
    float s = b3[o];
    for (int k = 0; k < H; ++k) s += z2[g * H + k] * W3[k * OUTC + o];
    out[t] = s;
  }
}

extern "C" void kernel_launch(void* const* d_in, const int* in_sizes, int n_in,
                              void* d_out, int out_size, void* d_ws, size_t ws_size,
                              hipStream_t stream) {
  const float* x     = (const float*)d_in[0];
  const int*   ei    = (const int*)d_in[1];
  const int*   srcp  = ei;
  const int*   dstp  = ei + E;
  const int*   batch = (const int*)d_in[2];
  const float* convW = (const float*)d_in[3];
  const float* convb = (const float*)d_in[4];
  const float* bng   = (const float*)d_in[5];
  const float* bnb   = (const float*)d_in[6];
  const float* W1    = (const float*)d_in[7];
  const float* b1    = (const float*)d_in[8];
  const float* hg    = (const float*)d_in[9];
  const float* hb    = (const float*)d_in[10];
  const float* W2    = (const float*)d_in[11];
  const float* b2    = (const float*)d_in[12];
  const float* W3    = (const float*)d_in[13];
  const float* b3    = (const float*)d_in[14];
  float* out = (float*)d_out;

  float*    ws     = (float*)d_ws;
  float*    agg    = ws;                                // N*H fp32
  float*    hWs    = agg + (size_t)N * H;               // N*H fp32
  ushort_t* WThi   = (ushort_t*)(hWs + (size_t)N * H);  // L*H*H bf16
  ushort_t* WTlo   = WThi + (size_t)L * H * H;          // L*H*H bf16
  float*    dinv   = (float*)(WTlo + (size_t)L * H * H);   // N
  int*      rowptr = (int*)(dinv + N);                  // N+1
  int*      csr    = rowptr + N + 1;                    // E
  int*      deg    = csr + E;                           // N   <- zero region start
  int*      cursor = deg + N;                           // N
  float*    bnsums = (float*)(cursor + N);              // (L-1)*256
  float*    pooled = bnsums + (L - 1) * 256;            // G*H <- zero region end
  float*    cnt    = pooled + G * H;                    // G
  float*    z1     = cnt + G;                           // G*H
  float*    z2     = z1 + G * H;                        // G*H
  int*      bsum   = (int*)(z2 + G * H);                // SCAN_B

  const size_t zero_bytes = (size_t)(N + N + (L - 1) * 256 + G * H) * 4;
  hipMemsetAsync(deg, 0, zero_bytes, stream);
  deg_count_kernel<<<(E + 255) / 256, 256, 0, stream>>>(dstp, deg);
  scanA_kernel<<<SCAN_B, 256, 0, stream>>>(deg, bsum, dinv);
  scanC_kernel<<<SCAN_B, 256, 0, stream>>>(deg, bsum, rowptr);
  csr_fill_kernel<<<(E + 255) / 256, 256, 0, stream>>>(srcp, dstp, rowptr, cursor, csr);
  prep_kernel<<<(L * H * H + 255) / 256, 256, 0, stream>>>(convW, WThi, WTlo);
  cnt_kernel<<<1, 128, 0, stream>>>(batch, cnt);

  for (int l = 0; l < L; ++l) {
    const float* A  = (l == 0) ? x : agg;
    const float* bs = (l == 0) ? nullptr : bnsums + (l - 1) * 256;
    const float* ga = (l == 0) ? nullptr : bng + (size_t)(l - 1) * H;
    const float* be = (l == 0) ? nullptr : bnb + (size_t)(l - 1) * H;
    gemm_mfma_kernel<<<(N + 63) / 64, 256, 0, stream>>>(
        A, WThi + (size_t)l * H * H, WTlo + (size_t)l * H * H, dinv, hWs, bs, ga, be);
    gather_kernel<<<N * 32 / 256, 256, 0, stream>>>(
        hWs, csr, rowptr, dinv, convb + (size_t)l * H, agg);
    if (l < L - 1)
      bn_stats_kernel<<<(N + 127) / 128, 256, 0, stream>>>(agg, bnsums + l * 256);
  }

  pool_kernel<<<(N + 127) / 128, 256, 0, stream>>>(agg, batch, pooled);
  head1_kernel<<<32, 256, 0, stream>>>(pooled, cnt, W1, b1, z1);
  head_bn_kernel<<<1, 128, 0, stream>>>(z1, hg, hb);
  head2_kernel<<<32, 256, 0, stream>>>(z1, W2, b2, z2);
  head3_kernel<<<3, 256, 0, stream>>>(z2, W3, b3, out);
}

// Round 10
// 890.769 us; speedup vs baseline: 1.0843x; 1.0843x over previous
//
#include <hip/hip_runtime.h>

#define N 50000
#define E 800000
#define H 128
#define G 64
#define OUTC 10
#define L 6
#define EPS 1e-5f

typedef unsigned short ushort_t;
typedef __attribute__((ext_vector_type(8))) short short8;
typedef __attribute__((ext_vector_type(8))) unsigned short ushort8;
typedef __attribute__((ext_vector_type(4))) float floatx4;

__device__ __forceinline__ void atomAddF(float* p, float v) {
  unsafeAtomicAdd(p, v);   // hw global_atomic_add_f32 on gfx950
}

__device__ __forceinline__ unsigned short f2bf(float f) {
  unsigned u = __float_as_uint(f);
  unsigned r = (u + 0x7FFF + ((u >> 16) & 1)) >> 16;  // RNE
  return (unsigned short)r;
}
__device__ __forceinline__ float bf2f(unsigned short b) {
  return __uint_as_float(((unsigned)b) << 16);
}

// ---------------- init ----------------
__global__ void deg_count_kernel(const int* __restrict__ dst, int* __restrict__ deg) {
  int e = blockIdx.x * blockDim.x + threadIdx.x;
  if (e < E) atomicAdd(&deg[dst[e]], 1);
}

// prep: conv_W -> bf16x2 split, transposed: WThi/WTlo [l][n][k]
__global__ void prep_kernel(const float* __restrict__ convW,
                            ushort_t* __restrict__ WThi, ushort_t* __restrict__ WTlo) {
  int j = blockIdx.x * 256 + threadIdx.x;
  if (j < L * H * H) {
    int l = j >> 14, r = j & 16383;   // H*H = 16384
    int n = r >> 7, k = r & 127;
    float w = convW[l * 16384 + k * 128 + n];
    unsigned short hi = f2bf(w);
    WThi[j] = hi;
    WTlo[j] = f2bf(w - bf2f(hi));
  }
}

// ---------------- scan: deg[N] -> rowptr[N+1]  (2 kernels) ----------------
#define SCAN_B ((N + 255) / 256)   // 196

__global__ __launch_bounds__(256) void scanA_kernel(const int* __restrict__ deg,
                                                    int* __restrict__ blocksum,
                                                    float* __restrict__ dinv) {
  __shared__ int red[256];
  int i = blockIdx.x * 256 + threadIdx.x;
  int v = (i < N) ? deg[i] : 0;
  if (i < N) dinv[i] = rsqrtf((float)(v + 1));
  red[threadIdx.x] = v;
  __syncthreads();
  for (int off = 128; off > 0; off >>= 1) {
    if (threadIdx.x < off) red[threadIdx.x] += red[threadIdx.x + off];
    __syncthreads();
  }
  if (threadIdx.x == 0) blocksum[blockIdx.x] = red[0];
}

__global__ __launch_bounds__(256) void scanC_kernel(const int* __restrict__ deg,
                                                    const int* __restrict__ blocksum,
                                                    int* __restrict__ rowptr) {
  __shared__ int pre[256];
  __shared__ int sh[256];
  const int bid = blockIdx.x, t = threadIdx.x;
  pre[t] = (t < bid) ? blocksum[t] : 0;   // bid < SCAN_B <= 256
  __syncthreads();
  for (int off = 128; off > 0; off >>= 1) {
    if (t < off) pre[t] += pre[t + off];
    __syncthreads();
  }
  int base = pre[0];
  int i = bid * 256 + t;
  int d = (i < N) ? deg[i] : 0;
  sh[t] = d;
  __syncthreads();
  for (int off = 1; off < 256; off <<= 1) {
    int v = (t >= off) ? sh[t - off] : 0;
    __syncthreads();
    sh[t] += v;
    __syncthreads();
  }
  if (i < N) rowptr[i] = base + sh[t] - d;
  if (i == 0) rowptr[N] = E;
}

__global__ void csr_fill_kernel(const int* __restrict__ src, const int* __restrict__ dst,
                                const int* __restrict__ rowptr,
                                int* __restrict__ cursor, int* __restrict__ csr) {
  int e = blockIdx.x * blockDim.x + threadIdx.x;
  if (e < E) {
    int d = dst[e];
    int pos = rowptr[d] + atomicAdd(&cursor[d], 1);
    csr[pos] = src[e];
  }
}

__global__ void cnt_kernel(const int* __restrict__ batch, float* __restrict__ cnt) {
  __shared__ int lb[G + 1];
  int t = threadIdx.x;  // 128 threads
  if (t <= G) {
    int lo = 0, hi = N;
    while (lo < hi) { int m = (lo + hi) >> 1; if (batch[m] < t) lo = m + 1; else hi = m; }
    lb[t] = lo;
  }
  __syncthreads();
  if (t < G) cnt[t] = (float)(lb[t + 1] - lb[t]);
}

// ---------------- MFMA GEMM (bf16x3 split precision, fp32-equivalent) ----------------
// hWs[row] = bf16( dinv[row] * (f(A)@W)[row] )   -- the ONLY per-layer quantization
// A fp32; f = identity (bnsums==null) or BN+ReLU in fp32 on A fragments.
// A = Ahi + Alo, W = Whi + Wlo (bf16 RNE + residual); D = Ahi*Whi + Ahi*Wlo + Alo*Whi.
// block: 256 thr = 4 waves; block tile 64 rows; wave tile 16 rows x 128 cols.
// A frag: A[m=lane&15][k=quad*8+j]; C/D: col=lane&15, row=quad*4+reg.
__global__ __launch_bounds__(256) void gemm_mfma_kernel(
    const float* __restrict__ A,
    const ushort_t* __restrict__ WThi, const ushort_t* __restrict__ WTlo,
    const float* __restrict__ dinv, ushort_t* __restrict__ hWs,
    const float* __restrict__ bnsums, const float* __restrict__ gamma,
    const float* __restrict__ beta)
{
  const int tid = threadIdx.x;
  const int wave = tid >> 6, lane = tid & 63;
  const int quad = lane >> 4, m = lane & 15;
  const int row0 = blockIdx.x * 64 + wave * 16;
  const int arow = min(row0 + m, N - 1);
  const float invN = 1.0f / (float)N;

  short8 ahi[4], alo[4];
#pragma unroll
  for (int kc = 0; kc < 4; ++kc) {
    const int k0 = kc * 32 + quad * 8;
    float4 f0 = *(const float4*)&A[arow * H + k0];
    float4 f1 = *(const float4*)&A[arow * H + k0 + 4];
    float vals[8] = {f0.x, f0.y, f0.z, f0.w, f1.x, f1.y, f1.z, f1.w};
    if (bnsums) {
#pragma unroll
      for (int j = 0; j < 8; ++j) {
        float s = bnsums[k0 + j], q = bnsums[128 + k0 + j];
        float mu = s * invN;
        float var = q * invN - mu * mu;
        float rs = rsqrtf(var + EPS);
        float sc = gamma[k0 + j] * rs;
        float sh = beta[k0 + j] - mu * sc;
        vals[j] = fmaxf(vals[j] * sc + sh, 0.f);
      }
    }
    short8 h, l;
#pragma unroll
    for (int j = 0; j < 8; ++j) {
      unsigned short hb = f2bf(vals[j]);
      h[j] = (short)hb;
      l[j] = (short)f2bf(vals[j] - bf2f(hb));
    }
    ahi[kc] = h;
    alo[kc] = l;
  }

  float dv[4];
#pragma unroll
  for (int i = 0; i < 4; ++i) {
    int r = row0 + quad * 4 + i;
    dv[i] = (r < N) ? dinv[r] : 0.f;
  }

  const short* WH = (const short*)WThi;
  const short* WL = (const short*)WTlo;
#pragma unroll
  for (int nt = 0; nt < 8; ++nt) {
    floatx4 acc = {0.f, 0.f, 0.f, 0.f};
#pragma unroll
    for (int kc = 0; kc < 4; ++kc) {
      const int boff = (nt * 16 + m) * H + kc * 32 + quad * 8;
      short8 bhi = *(const short8*)&WH[boff];
      short8 blo = *(const short8*)&WL[boff];
      acc = __builtin_amdgcn_mfma_f32_16x16x32_bf16(ahi[kc], bhi, acc, 0, 0, 0);
      acc = __builtin_amdgcn_mfma_f32_16x16x32_bf16(alo[kc], bhi, acc, 0, 0, 0);
      acc = __builtin_amdgcn_mfma_f32_16x16x32_bf16(ahi[kc], blo, acc, 0, 0, 0);
    }
    int col = nt * 16 + m;
#pragma unroll
    for (int i = 0; i < 4; ++i) {
      int r = row0 + quad * 4 + i;
      if (r < N) hWs[r * H + col] = f2bf(acc[i] * dv[i]);
    }
  }
}

// ---------------- CSR gather (bf16 in, fp32 out) ----------------
// agg[n] = dinv[n]*(sum_e hWs[src_e] + hWs[n]) + bias
// 16 lanes per node, 8 channels (ushort8 = 16B) per lane; grid exact (N*16/256 = 3125)
__global__ __launch_bounds__(256) void gather_kernel(
    const ushort_t* __restrict__ hWs, const int* __restrict__ csr,
    const int* __restrict__ rowptr, const float* __restrict__ dinv,
    const float* __restrict__ bias, float* __restrict__ agg)
{
  int t = blockIdx.x * 256 + threadIdx.x;
  int n = t >> 4, c8 = (t & 15) * 8;

  ushort8 us = *(const ushort8*)&hWs[n * H + c8];
  float acc[8];
#pragma unroll
  for (int j = 0; j < 8; ++j) acc[j] = bf2f(us[j]);

  int e = rowptr[n], end = rowptr[n + 1];
  for (; e + 7 < end; e += 8) {
    int s0 = csr[e], s1 = csr[e + 1], s2 = csr[e + 2], s3 = csr[e + 3];
    int s4 = csr[e + 4], s5 = csr[e + 5], s6 = csr[e + 6], s7 = csr[e + 7];
    ushort8 u0 = *(const ushort8*)&hWs[s0 * H + c8];
    ushort8 u1 = *(const ushort8*)&hWs[s1 * H + c8];
    ushort8 u2 = *(const ushort8*)&hWs[s2 * H + c8];
    ushort8 u3 = *(const ushort8*)&hWs[s3 * H + c8];
    ushort8 u4 = *(const ushort8*)&hWs[s4 * H + c8];
    ushort8 u5 = *(const ushort8*)&hWs[s5 * H + c8];
    ushort8 u6 = *(const ushort8*)&hWs[s6 * H + c8];
    ushort8 u7 = *(const ushort8*)&hWs[s7 * H + c8];
#pragma unroll
    for (int j = 0; j < 8; ++j)
      acc[j] += ((bf2f(u0[j]) + bf2f(u1[j])) + (bf2f(u2[j]) + bf2f(u3[j]))) +
                ((bf2f(u4[j]) + bf2f(u5[j])) + (bf2f(u6[j]) + bf2f(u7[j])));
  }
  for (; e + 1 < end; e += 2) {
    int s0 = csr[e], s1 = csr[e + 1];
    ushort8 u0 = *(const ushort8*)&hWs[s0 * H + c8];
    ushort8 u1 = *(const ushort8*)&hWs[s1 * H + c8];
#pragma unroll
    for (int j = 0; j < 8; ++j) acc[j] += bf2f(u0[j]) + bf2f(u1[j]);
  }
  if (e < end) {
    int s0 = csr[e];
    ushort8 u0 = *(const ushort8*)&hWs[s0 * H + c8];
#pragma unroll
    for (int j = 0; j < 8; ++j) acc[j] += bf2f(u0[j]);
  }

  float dn = dinv[n];
  float4 b0 = *(const float4*)&bias[c8];
  float4 b1 = *(const float4*)&bias[c8 + 4];
  float bb[8] = {b0.x, b0.y, b0.z, b0.w, b1.x, b1.y, b1.z, b1.w};
  float4 o0 = make_float4(acc[0] * dn + bb[0], acc[1] * dn + bb[1],
                          acc[2] * dn + bb[2], acc[3] * dn + bb[3]);
  float4 o1 = make_float4(acc[4] * dn + bb[4], acc[5] * dn + bb[5],
                          acc[6] * dn + bb[6], acc[7] * dn + bb[7]);
  *(float4*)&agg[n * H + c8] = o0;
  *(float4*)&agg[n * H + c8 + 4] = o1;
}

// ---------------- batchnorm stats over fp32 agg (float4 loads) ----------------
// 391 blocks x 128 rows; thread: 4 channels x 16 row-iters; 256 atomics/block
__global__ __launch_bounds__(256) void bn_stats_kernel(
    const float* __restrict__ a, float* __restrict__ sums)
{
  __shared__ float4 sred[256], qred[256];
  int tid = threadIdx.x;
  int c4 = (tid & 31) * 4, rg = tid >> 5;   // 8 row groups
  int r0 = blockIdx.x * 128;
  float4 s = make_float4(0.f, 0.f, 0.f, 0.f);
  float4 q = make_float4(0.f, 0.f, 0.f, 0.f);
  for (int i = 0; i < 16; ++i) {
    int r = r0 + i * 8 + rg;
    if (r < N) {
      float4 v = *(const float4*)&a[r * H + c4];
      s.x += v.x; s.y += v.y; s.z += v.z; s.w += v.w;
      q.x += v.x * v.x; q.y += v.y * v.y; q.z += v.z * v.z; q.w += v.w * v.w;
    }
  }
  sred[tid] = s; qred[tid] = q;
  __syncthreads();
  if (tid < 32) {
    float4 S = sred[tid], Q = qred[tid];
#pragma unroll
    for (int g = 1; g < 8; ++g) {
      float4 s2 = sred[g * 32 + tid], q2 = qred[g * 32 + tid];
      S.x += s2.x; S.y += s2.y; S.z += s2.z; S.w += s2.w;
      Q.x += q2.x; Q.y += q2.y; Q.z += q2.z; Q.w += q2.w;
    }
    int c = tid * 4;
    atomAddF(&sums[c + 0], S.x); atomAddF(&sums[c + 1], S.y);
    atomAddF(&sums[c + 2], S.z); atomAddF(&sums[c + 3], S.w);
    atomAddF(&sums[128 + c + 0], Q.x); atomAddF(&sums[128 + c + 1], Q.y);
    atomAddF(&sums[128 + c + 2], Q.z); atomAddF(&sums[128 + c + 3], Q.w);
  }
}

// ---------------- global mean pool: chunked run-length accumulate (batch sorted) --------
__global__ __launch_bounds__(256) void pool_kernel(
    const float* __restrict__ h, const int* __restrict__ batch,
    float* __restrict__ pooled /* pre-zeroed */)
{
  int r0 = blockIdx.x * 128;
  int rend = min(r0 + 128, N);
  int c = threadIdx.x & 127, half = threadIdx.x >> 7;
  float acc = 0.f;
  int curg = -1;
  for (int r = r0 + half; r < rend; r += 2) {
    int g = batch[r];
    if (g != curg) {
      if (curg >= 0) atomAddF(&pooled[curg * H + c], acc);
      acc = 0.f; curg = g;
    }
    acc += h[r * H + c];
  }
  if (curg >= 0) atomAddF(&pooled[curg * H + c], acc);
}

// ---------------- head (4 small kernels, parallel across CUs) ----------------
__global__ void head1_kernel(const float* __restrict__ pooled, const float* __restrict__ cnt,
                             const float* __restrict__ W1, const float* __restrict__ b1,
                             float* __restrict__ z1)
{
  int t = blockIdx.x * 256 + threadIdx.x;  // 8192
  int g = t >> 7, c = t & 127;
  float s = 0.f;
  for (int k = 0; k < H; ++k) s += pooled[g * H + k] * W1[k * H + c];
  z1[t] = s / fmaxf(cnt[g], 1.0f) + b1[c];
}

__global__ void head_bn_kernel(float* __restrict__ z1,
                               const float* __restrict__ gamma, const float* __restrict__ beta)
{
  int c = threadIdx.x;  // 128 threads
  float s = 0.f, q = 0.f;
  for (int g = 0; g < G; ++g) { float v = z1[g * H + c]; s += v; q += v * v; }
  float mu = s / (float)G;
  float var = q / (float)G - mu * mu;
  float rs = rsqrtf(var + EPS);
  float ga = gamma[c], be = beta[c];
  for (int g = 0; g < G; ++g) {
    float v = z1[g * H + c];
    z1[g * H + c] = fmaxf((v - mu) * rs * ga + be, 0.f);
  }
}

__global__ void head2_kernel(const float* __restrict__ z1, const float* __restrict__ W2,
                             const float* __restrict__ b2, float* __restrict__ z2)
{
  int t = blockIdx.x * 256 + threadIdx.x;  // 8192
  int g = t >> 7, c = t & 127;
  float s = b2[c];
  for (int k = 0; k < H; ++k) s += z1[g * H + k] * W2[k * H + c];
  z2[t] = fmaxf(s, 0.f);
}

__global__ void head3_kernel(const float* __restrict__ z2, const float* __restrict__ W3,
                             const float* __restrict__ b3, float* __restrict__ out)
{
  int t = blockIdx.x * 256 + threadIdx.x;
  if (t < G * OUTC) {
    int g = t / OUTC, o = t % OUTC;
    float s = b3[o];
    for (int k = 0; k < H; ++k) s += z2[g * H + k] * W3[k * OUTC + o];
    out[t] = s;
  }
}

extern "C" void kernel_launch(void* const* d_in, const int* in_sizes, int n_in,
                              void* d_out, int out_size, void* d_ws, size_t ws_size,
                              hipStream_t stream) {
  const float* x     = (const float*)d_in[0];
  const int*   ei    = (const int*)d_in[1];
  const int*   srcp  = ei;
  const int*   dstp  = ei + E;
  const int*   batch = (const int*)d_in[2];
  const float* convW = (const float*)d_in[3];
  const float* convb = (const float*)d_in[4];
  const float* bng   = (const float*)d_in[5];
  const float* bnb   = (const float*)d_in[6];
  const float* W1    = (const float*)d_in[7];
  const float* b1    = (const float*)d_in[8];
  const float* hg    = (const float*)d_in[9];
  const float* hb    = (const float*)d_in[10];
  const float* W2    = (const float*)d_in[11];
  const float* b2    = (const float*)d_in[12];
  const float* W3    = (const float*)d_in[13];
  const float* b3    = (const float*)d_in[14];
  float* out = (float*)d_out;

  float*    ws     = (float*)d_ws;
  float*    agg    = ws;                                // N*H fp32
  ushort_t* hWs    = (ushort_t*)(agg + (size_t)N * H);  // N*H bf16
  ushort_t* WThi   = hWs + (size_t)N * H;               // L*H*H bf16
  ushort_t* WTlo   = WThi + (size_t)L * H * H;          // L*H*H bf16
  float*    dinv   = (float*)(WTlo + (size_t)L * H * H);   // N
  int*      rowptr = (int*)(dinv + N);                  // N+1
  int*      csr    = rowptr + N + 1;                    // E
  int*      deg    = csr + E;                           // N   <- zero region start
  int*      cursor = deg + N;                           // N
  float*    bnsums = (float*)(cursor + N);              // (L-1)*256
  float*    pooled = bnsums + (L - 1) * 256;            // G*H <- zero region end
  float*    cnt    = pooled + G * H;                    // G
  float*    z1     = cnt + G;                           // G*H
  float*    z2     = z1 + G * H;                        // G*H
  int*      bsum   = (int*)(z2 + G * H);                // SCAN_B

  const size_t zero_bytes = (size_t)(N + N + (L - 1) * 256 + G * H) * 4;
  hipMemsetAsync(deg, 0, zero_bytes, stream);
  deg_count_kernel<<<(E + 255) / 256, 256, 0, stream>>>(dstp, deg);
  scanA_kernel<<<SCAN_B, 256, 0, stream>>>(deg, bsum, dinv);
  scanC_kernel<<<SCAN_B, 256, 0, stream>>>(deg, bsum, rowptr);
  csr_fill_kernel<<<(E + 255) / 256, 256, 0, stream>>>(srcp, dstp, rowptr, cursor, csr);
  prep_kernel<<<(L * H * H + 255) / 256, 256, 0, stream>>>(convW, WThi, WTlo);
  cnt_kernel<<<1, 128, 0, stream>>>(batch, cnt);

  for (int l = 0; l < L; ++l) {
    const float* A  = (l == 0) ? x : agg;
    const float* bs = (l == 0) ? nullptr : bnsums + (l - 1) * 256;
    const float* ga = (l == 0) ? nullptr : bng + (size_t)(l - 1) * H;
    const float* be = (l == 0) ? nullptr : bnb + (size_t)(l - 1) * H;
    gemm_mfma_kernel<<<(N + 63) / 64, 256, 0, stream>>>(
        A, WThi + (size_t)l * H * H, WTlo + (size_t)l * H * H, dinv, hWs, bs, ga, be);
    gather_kernel<<<N * 16 / 256, 256, 0, stream>>>(
        hWs, csr, rowptr, dinv, convb + (size_t)l * H, agg);
    if (l < L - 1)
      bn_stats_kernel<<<(N + 127) / 128, 256, 0, stream>>>(agg, bnsums + l * 256);
  }

  pool_kernel<<<(N + 127) / 128, 256, 0, stream>>>(agg, batch, pooled);
  head1_kernel<<<32, 256, 0, stream>>>(pooled, cnt, W1, b1, z1);
  head_bn_kernel<<<1, 128, 0, stream>>>(z1, hg, hb);
  head2_kernel<<<32, 256, 0, stream>>>(z1, W2, b2, z2);
  head3_kernel<<<3, 256, 0, stream>>>(z2, W3, b3, out);
}

// Round 11
// 746.547 us; speedup vs baseline: 1.2938x; 1.1932x over previous
//
#include <hip/hip_runtime.h>

#define N 50000
#define E 800000
#define H 128
#define G 64
#define OUTC 10
#define L 6
#define EPS 1e-5f

#define GB 3125            // gather blocks = N/16
#define RB 64              // bn_reduce blocks
#define RCHUNK 49          // ceil(GB/RB)

typedef unsigned short ushort_t;
typedef __attribute__((ext_vector_type(8))) short short8;
typedef __attribute__((ext_vector_type(8))) unsigned short ushort8;
typedef __attribute__((ext_vector_type(4))) float floatx4;

__device__ __forceinline__ void atomAddF(float* p, float v) {
  unsafeAtomicAdd(p, v);   // hw global_atomic_add_f32 on gfx950
}

__device__ __forceinline__ unsigned short f2bf(float f) {
  unsigned u = __float_as_uint(f);
  unsigned r = (u + 0x7FFF + ((u >> 16) & 1)) >> 16;  // RNE
  return (unsigned short)r;
}
__device__ __forceinline__ float bf2f(unsigned short b) {
  return __uint_as_float(((unsigned)b) << 16);
}

// ---------------- init ----------------
__global__ void deg_count_kernel(const int* __restrict__ dst, int* __restrict__ deg) {
  int e = blockIdx.x * blockDim.x + threadIdx.x;
  if (e < E) atomicAdd(&deg[dst[e]], 1);
}

// prep: conv_W -> bf16x2 split, transposed: WThi/WTlo [l][n][k]
__global__ void prep_kernel(const float* __restrict__ convW,
                            ushort_t* __restrict__ WThi, ushort_t* __restrict__ WTlo) {
  int j = blockIdx.x * 256 + threadIdx.x;
  if (j < L * H * H) {
    int l = j >> 14, r = j & 16383;   // H*H = 16384
    int n = r >> 7, k = r & 127;
    float w = convW[l * 16384 + k * 128 + n];
    unsigned short hi = f2bf(w);
    WThi[j] = hi;
    WTlo[j] = f2bf(w - bf2f(hi));
  }
}

// ---------------- scan: deg[N] -> rowptr[N+1]  (2 kernels) ----------------
#define SCAN_B ((N + 255) / 256)   // 196

__global__ __launch_bounds__(256) void scanA_kernel(const int* __restrict__ deg,
                                                    int* __restrict__ blocksum,
                                                    float* __restrict__ dinv) {
  __shared__ int red[256];
  int i = blockIdx.x * 256 + threadIdx.x;
  int v = (i < N) ? deg[i] : 0;
  if (i < N) dinv[i] = rsqrtf((float)(v + 1));
  red[threadIdx.x] = v;
  __syncthreads();
  for (int off = 128; off > 0; off >>= 1) {
    if (threadIdx.x < off) red[threadIdx.x] += red[threadIdx.x + off];
    __syncthreads();
  }
  if (threadIdx.x == 0) blocksum[blockIdx.x] = red[0];
}

__global__ __launch_bounds__(256) void scanC_kernel(const int* __restrict__ deg,
                                                    const int* __restrict__ blocksum,
                                                    int* __restrict__ rowptr) {
  __shared__ int pre[256];
  __shared__ int sh[256];
  const int bid = blockIdx.x, t = threadIdx.x;
  pre[t] = (t < bid) ? blocksum[t] : 0;   // bid < SCAN_B <= 256
  __syncthreads();
  for (int off = 128; off > 0; off >>= 1) {
    if (t < off) pre[t] += pre[t + off];
    __syncthreads();
  }
  int base = pre[0];
  int i = bid * 256 + t;
  int d = (i < N) ? deg[i] : 0;
  sh[t] = d;
  __syncthreads();
  for (int off = 1; off < 256; off <<= 1) {
    int v = (t >= off) ? sh[t - off] : 0;
    __syncthreads();
    sh[t] += v;
    __syncthreads();
  }
  if (i < N) rowptr[i] = base + sh[t] - d;
  if (i == 0) rowptr[N] = E;
}

__global__ void csr_fill_kernel(const int* __restrict__ src, const int* __restrict__ dst,
                                const int* __restrict__ rowptr,
                                int* __restrict__ cursor, int* __restrict__ csr) {
  int e = blockIdx.x * blockDim.x + threadIdx.x;
  if (e < E) {
    int d = dst[e];
    int pos = rowptr[d] + atomicAdd(&cursor[d], 1);
    csr[pos] = src[e];
  }
}

__global__ void cnt_kernel(const int* __restrict__ batch, float* __restrict__ cnt) {
  __shared__ int lb[G + 1];
  int t = threadIdx.x;  // 128 threads
  if (t <= G) {
    int lo = 0, hi = N;
    while (lo < hi) { int m = (lo + hi) >> 1; if (batch[m] < t) lo = m + 1; else hi = m; }
    lb[t] = lo;
  }
  __syncthreads();
  if (t < G) cnt[t] = (float)(lb[t + 1] - lb[t]);
}

// ---------------- MFMA GEMM (bf16x3 split precision, fp32-equivalent) ----------------
// hWs[row] = bf16( dinv[row] * (f(A)@W)[row] )   -- the ONLY per-layer quantization
// A fp32; f = identity (bnsums==null) or BN+ReLU in fp32 on A fragments.
__global__ __launch_bounds__(256) void gemm_mfma_kernel(
    const float* __restrict__ A,
    const ushort_t* __restrict__ WThi, const ushort_t* __restrict__ WTlo,
    const float* __restrict__ dinv, ushort_t* __restrict__ hWs,
    const float* __restrict__ bnsums, const float* __restrict__ gamma,
    const float* __restrict__ beta)
{
  const int tid = threadIdx.x;
  const int wave = tid >> 6, lane = tid & 63;
  const int quad = lane >> 4, m = lane & 15;
  const int row0 = blockIdx.x * 64 + wave * 16;
  const int arow = min(row0 + m, N - 1);
  const float invN = 1.0f / (float)N;

  short8 ahi[4], alo[4];
#pragma unroll
  for (int kc = 0; kc < 4; ++kc) {
    const int k0 = kc * 32 + quad * 8;
    float4 f0 = *(const float4*)&A[arow * H + k0];
    float4 f1 = *(const float4*)&A[arow * H + k0 + 4];
    float vals[8] = {f0.x, f0.y, f0.z, f0.w, f1.x, f1.y, f1.z, f1.w};
    if (bnsums) {
#pragma unroll
      for (int j = 0; j < 8; ++j) {
        float s = bnsums[k0 + j], q = bnsums[128 + k0 + j];
        float mu = s * invN;
        float var = q * invN - mu * mu;
        float rs = rsqrtf(var + EPS);
        float sc = gamma[k0 + j] * rs;
        float sh = beta[k0 + j] - mu * sc;
        vals[j] = fmaxf(vals[j] * sc + sh, 0.f);
      }
    }
    short8 h, l;
#pragma unroll
    for (int j = 0; j < 8; ++j) {
      unsigned short hb = f2bf(vals[j]);
      h[j] = (short)hb;
      l[j] = (short)f2bf(vals[j] - bf2f(hb));
    }
    ahi[kc] = h;
    alo[kc] = l;
  }

  float dv[4];
#pragma unroll
  for (int i = 0; i < 4; ++i) {
    int r = row0 + quad * 4 + i;
    dv[i] = (r < N) ? dinv[r] : 0.f;
  }

  const short* WH = (const short*)WThi;
  const short* WL = (const short*)WTlo;
#pragma unroll
  for (int nt = 0; nt < 8; ++nt) {
    floatx4 acc = {0.f, 0.f, 0.f, 0.f};
#pragma unroll
    for (int kc = 0; kc < 4; ++kc) {
      const int boff = (nt * 16 + m) * H + kc * 32 + quad * 8;
      short8 bhi = *(const short8*)&WH[boff];
      short8 blo = *(const short8*)&WL[boff];
      acc = __builtin_amdgcn_mfma_f32_16x16x32_bf16(ahi[kc], bhi, acc, 0, 0, 0);
      acc = __builtin_amdgcn_mfma_f32_16x16x32_bf16(alo[kc], bhi, acc, 0, 0, 0);
      acc = __builtin_amdgcn_mfma_f32_16x16x32_bf16(ahi[kc], blo, acc, 0, 0, 0);
    }
    int col = nt * 16 + m;
#pragma unroll
    for (int i = 0; i < 4; ++i) {
      int r = row0 + quad * 4 + i;
      if (r < N) hWs[r * H + col] = f2bf(acc[i] * dv[i]);
    }
  }
}

// ---------------- CSR gather + fused BN-stat partials ----------------
// agg[n] = dinv[n]*(sum_e hWs[src_e] + hWs[n]) + bias   (fp32 out)
// 16 lanes per node, 8 channels/lane; block = exactly 16 nodes (GB=3125 blocks).
// bnpart != null -> block writes non-atomic 128 sum + 128 sumsq partials.
__global__ __launch_bounds__(256) void gather_kernel(
    const ushort_t* __restrict__ hWs, const int* __restrict__ csr,
    const int* __restrict__ rowptr, const float* __restrict__ dinv,
    const float* __restrict__ bias, float* __restrict__ agg,
    float* __restrict__ bnpart)
{
  __shared__ float lsum[16][132];
  int t = blockIdx.x * 256 + threadIdx.x;
  int n = t >> 4, c8 = (t & 15) * 8;

  ushort8 us = *(const ushort8*)&hWs[n * H + c8];
  float acc[8];
#pragma unroll
  for (int j = 0; j < 8; ++j) acc[j] = bf2f(us[j]);

  int e = rowptr[n], end = rowptr[n + 1];
  for (; e + 7 < end; e += 8) {
    int s0 = csr[e], s1 = csr[e + 1], s2 = csr[e + 2], s3 = csr[e + 3];
    int s4 = csr[e + 4], s5 = csr[e + 5], s6 = csr[e + 6], s7 = csr[e + 7];
    ushort8 u0 = *(const ushort8*)&hWs[s0 * H + c8];
    ushort8 u1 = *(const ushort8*)&hWs[s1 * H + c8];
    ushort8 u2 = *(const ushort8*)&hWs[s2 * H + c8];
    ushort8 u3 = *(const ushort8*)&hWs[s3 * H + c8];
    ushort8 u4 = *(const ushort8*)&hWs[s4 * H + c8];
    ushort8 u5 = *(const ushort8*)&hWs[s5 * H + c8];
    ushort8 u6 = *(const ushort8*)&hWs[s6 * H + c8];
    ushort8 u7 = *(const ushort8*)&hWs[s7 * H + c8];
#pragma unroll
    for (int j = 0; j < 8; ++j)
      acc[j] += ((bf2f(u0[j]) + bf2f(u1[j])) + (bf2f(u2[j]) + bf2f(u3[j]))) +
                ((bf2f(u4[j]) + bf2f(u5[j])) + (bf2f(u6[j]) + bf2f(u7[j])));
  }
  for (; e + 1 < end; e += 2) {
    int s0 = csr[e], s1 = csr[e + 1];
    ushort8 u0 = *(const ushort8*)&hWs[s0 * H + c8];
    ushort8 u1 = *(const ushort8*)&hWs[s1 * H + c8];
#pragma unroll
    for (int j = 0; j < 8; ++j) acc[j] += bf2f(u0[j]) + bf2f(u1[j]);
  }
  if (e < end) {
    int s0 = csr[e];
    ushort8 u0 = *(const ushort8*)&hWs[s0 * H + c8];
#pragma unroll
    for (int j = 0; j < 8; ++j) acc[j] += bf2f(u0[j]);
  }

  float dn = dinv[n];
  float4 b0 = *(const float4*)&bias[c8];
  float4 b1 = *(const float4*)&bias[c8 + 4];
  float bb[8] = {b0.x, b0.y, b0.z, b0.w, b1.x, b1.y, b1.z, b1.w};
  float ov[8];
#pragma unroll
  for (int j = 0; j < 8; ++j) ov[j] = acc[j] * dn + bb[j];
  float4 o0 = make_float4(ov[0], ov[1], ov[2], ov[3]);
  float4 o1 = make_float4(ov[4], ov[5], ov[6], ov[7]);
  *(float4*)&agg[n * H + c8] = o0;
  *(float4*)&agg[n * H + c8 + 4] = o1;

  if (bnpart) {
    int nn = threadIdx.x >> 4;
#pragma unroll
    for (int j = 0; j < 8; ++j) lsum[nn][c8 + j] = ov[j];
    __syncthreads();
    int c = threadIdx.x;
    if (c < 128) {
      float s = 0.f;
#pragma unroll
      for (int k = 0; k < 16; ++k) s += lsum[k][c];
      bnpart[blockIdx.x * 256 + c] = s;
    } else {
      int cc = c - 128;
      float q = 0.f;
#pragma unroll
      for (int k = 0; k < 16; ++k) { float v = lsum[k][cc]; q += v * v; }
      bnpart[blockIdx.x * 256 + c] = q;
    }
  }
}

// ---------------- bn partial reduce: bnpart[GB][256] -> sums[256] ----------------
__global__ __launch_bounds__(256) void bn_reduce_kernel(
    const float* __restrict__ bnpart, float* __restrict__ sums /* pre-zeroed */)
{
  int c = threadIdx.x;
  int b0 = blockIdx.x * RCHUNK;
  int b1 = min(b0 + RCHUNK, GB);
  float s = 0.f;
  for (int b = b0; b < b1; ++b) s += bnpart[b * 256 + c];
  atomAddF(&sums[c], s);
}

// ---------------- global mean pool: chunked run-length accumulate (batch sorted) --------
__global__ __launch_bounds__(256) void pool_kernel(
    const float* __restrict__ h, const int* __restrict__ batch,
    float* __restrict__ pooled /* pre-zeroed */)
{
  int r0 = blockIdx.x * 128;
  int rend = min(r0 + 128, N);
  int c = threadIdx.x & 127, half = threadIdx.x >> 7;
  float acc = 0.f;
  int curg = -1;
  for (int r = r0 + half; r < rend; r += 2) {
    int g = batch[r];
    if (g != curg) {
      if (curg >= 0) atomAddF(&pooled[curg * H + c], acc);
      acc = 0.f; curg = g;
    }
    acc += h[r * H + c];
  }
  if (curg >= 0) atomAddF(&pooled[curg * H + c], acc);
}

// ---------------- head (4 small kernels, parallel across CUs) ----------------
__global__ void head1_kernel(const float* __restrict__ pooled, const float* __restrict__ cnt,
                             const float* __restrict__ W1, const float* __restrict__ b1,
                             float* __restrict__ z1)
{
  int t = blockIdx.x * 256 + threadIdx.x;  // 8192
  int g = t >> 7, c = t & 127;
  float s = 0.f;
  for (int k = 0; k < H; ++k) s += pooled[g * H + k] * W1[k * H + c];
  z1[t] = s / fmaxf(cnt[g], 1.0f) + b1[c];
}

__global__ void head_bn_kernel(float* __restrict__ z1,
                               const float* __restrict__ gamma, const float* __restrict__ beta)
{
  int c = threadIdx.x;  // 128 threads
  float s = 0.f, q = 0.f;
  for (int g = 0; g < G; ++g) { float v = z1[g * H + c]; s += v; q += v * v; }
  float mu = s / (float)G;
  float var = q / (float)G - mu * mu;
  float rs = rsqrtf(var + EPS);
  float ga = gamma[c], be = beta[c];
  for (int g = 0; g < G; ++g) {
    float v = z1[g * H + c];
    z1[g * H + c] = fmaxf((v - mu) * rs * ga + be, 0.f);
  }
}

__global__ void head2_kernel(const float* __restrict__ z1, const float* __restrict__ W2,
                             const float* __restrict__ b2, float* __restrict__ z2)
{
  int t = blockIdx.x * 256 + threadIdx.x;  // 8192
  int g = t >> 7, c = t & 127;
  float s = b2[c];
  for (int k = 0; k < H; ++k) s += z1[g * H + k] * W2[k * H + c];
  z2[t] = fmaxf(s, 0.f);
}

__global__ void head3_kernel(const float* __restrict__ z2, const float* __restrict__ W3,
                             const float* __restrict__ b3, float* __restrict__ out)
{
  int t = blockIdx.x * 256 + threadIdx.x;
  if (t < G * OUTC) {
    int g = t / OUTC, o = t % OUTC;
    float s = b3[o];
    for (int k = 0; k < H; ++k) s += z2[g * H + k] * W3[k * OUTC + o];
    out[t] = s;
  }
}

extern "C" void kernel_launch(void* const* d_in, const int* in_sizes, int n_in,
                              void* d_out, int out_size, void* d_ws, size_t ws_size,
                              hipStream_t stream) {
  const float* x     = (const float*)d_in[0];
  const int*   ei    = (const int*)d_in[1];
  const int*   srcp  = ei;
  const int*   dstp  = ei + E;
  const int*   batch = (const int*)d_in[2];
  const float* convW = (const float*)d_in[3];
  const float* convb = (const float*)d_in[4];
  const float* bng   = (const float*)d_in[5];
  const float* bnb   = (const float*)d_in[6];
  const float* W1    = (const float*)d_in[7];
  const float* b1    = (const float*)d_in[8];
  const float* hg    = (const float*)d_in[9];
  const float* hb    = (const float*)d_in[10];
  const float* W2    = (const float*)d_in[11];
  const float* b2    = (const float*)d_in[12];
  const float* W3    = (const float*)d_in[13];
  const float* b3    = (const float*)d_in[14];
  float* out = (float*)d_out;

  float*    ws     = (float*)d_ws;
  float*    agg    = ws;                                // N*H fp32
  ushort_t* hWs    = (ushort_t*)(agg + (size_t)N * H);  // N*H bf16
  ushort_t* WThi   = hWs + (size_t)N * H;               // L*H*H bf16
  ushort_t* WTlo   = WThi + (size_t)L * H * H;          // L*H*H bf16
  float*    dinv   = (float*)(WTlo + (size_t)L * H * H);   // N
  int*      rowptr = (int*)(dinv + N);                  // N+1
  int*      csr    = rowptr + N + 1;                    // E
  float*    bnpart = (float*)(csr + E);                 // GB*256
  int*      deg    = (int*)(bnpart + (size_t)GB * 256); // N   <- zero region start
  int*      cursor = deg + N;                           // N
  float*    bnsums = (float*)(cursor + N);              // (L-1)*256
  float*    pooled = bnsums + (L - 1) * 256;            // G*H <- zero region end
  float*    cnt    = pooled + G * H;                    // G
  float*    z1     = cnt + G;                           // G*H
  float*    z2     = z1 + G * H;                        // G*H
  int*      bsum   = (int*)(z2 + G * H);                // SCAN_B

  const size_t zero_bytes = (size_t)(N + N + (L - 1) * 256 + G * H) * 4;
  hipMemsetAsync(deg, 0, zero_bytes, stream);
  deg_count_kernel<<<(E + 255) / 256, 256, 0, stream>>>(dstp, deg);
  scanA_kernel<<<SCAN_B, 256, 0, stream>>>(deg, bsum, dinv);
  scanC_kernel<<<SCAN_B, 256, 0, stream>>>(deg, bsum, rowptr);
  csr_fill_kernel<<<(E + 255) / 256, 256, 0, stream>>>(srcp, dstp, rowptr, cursor, csr);
  prep_kernel<<<(L * H * H + 255) / 256, 256, 0, stream>>>(convW, WThi, WTlo);
  cnt_kernel<<<1, 128, 0, stream>>>(batch, cnt);

  for (int l = 0; l < L; ++l) {
    const float* A  = (l == 0) ? x : agg;
    const float* bs = (l == 0) ? nullptr : bnsums + (l - 1) * 256;
    const float* ga = (l == 0) ? nullptr : bng + (size_t)(l - 1) * H;
    const float* be = (l == 0) ? nullptr : bnb + (size_t)(l - 1) * H;
    gemm_mfma_kernel<<<(N + 63) / 64, 256, 0, stream>>>(
        A, WThi + (size_t)l * H * H, WTlo + (size_t)l * H * H, dinv, hWs, bs, ga, be);
    bool last = (l == L - 1);
    gather_kernel<<<GB, 256, 0, stream>>>(
        hWs, csr, rowptr, dinv, convb + (size_t)l * H, agg, last ? nullptr : bnpart);
    if (!last)
      bn_reduce_kernel<<<RB, 256, 0, stream>>>(bnpart, bnsums + l * 256);
  }

  pool_kernel<<<(N + 127) / 128, 256, 0, stream>>>(agg, batch, pooled);
  head1_kernel<<<32, 256, 0, stream>>>(pooled, cnt, W1, b1, z1);
  head_bn_kernel<<<1, 128, 0, stream>>>(z1, hg, hb);
  head2_kernel<<<32, 256, 0, stream>>>(z1, W2, b2, z2);
  head3_kernel<<<3, 256, 0, stream>>>(z2, W3, b3, out);
}